// Round 15
// baseline (180.566 us; speedup 1.0000x reference)
//
#include <hip/hip_runtime.h>
#include <hip/hip_bf16.h>

#define N_NODES 20000
#define N_EDGES 640000
#define HIDDEN 256
#define HEADS 8
#define HEAD_DIM 32
#define N_FEATS 9
#define VOCAB 119

typedef __hip_bfloat16 bf16;
typedef __attribute__((ext_vector_type(8))) short short8;
typedef __attribute__((ext_vector_type(4))) float f32x4;
typedef __attribute__((ext_vector_type(2))) float f32x2;

__device__ __forceinline__ ushort f2u(float x) { union { ushort u; bf16 b; } c; c.b = __float2bfloat16(x); return c.u; }

// packed f32 math (CDNA: full-rate 2x FMA per instr)
__device__ __forceinline__ f32x2 pk_fma(f32x2 a, f32x2 b, f32x2 c) {
    f32x2 d;
    asm("v_pk_fma_f32 %0, %1, %2, %3" : "=v"(d) : "v"(a), "v"(b), "v"(c));
    return d;
}
__device__ __forceinline__ f32x2 pk_add(f32x2 a, f32x2 b) {
    f32x2 d;
    asm("v_pk_add_f32 %0, %1, %2" : "=v"(d) : "v"(a), "v"(b));
    return d;
}

// DPP cross-lane fetch (VALU pipe). 0xB1=quad_perm xor1, 0x4E=quad_perm xor2,
// 0x124=row_ror:4, 0x128=row_ror:8 (rotation-reduce within 16-lane rows).
template <int CTRL>
__device__ __forceinline__ float dpp_xor(float v) {
    return __int_as_float(__builtin_amdgcn_update_dpp(
        0, __float_as_int(v), CTRL, 0xf, 0xf, true));
}

__device__ __forceinline__ float fast_exp2(float x) {
#if __has_builtin(__builtin_amdgcn_exp2f)
    return __builtin_amdgcn_exp2f(x);
#else
    return exp2f(x);
#endif
}

// hard scheduling fence; ONLY at end of a wave's load batch (R7 lesson).
__device__ __forceinline__ void sched_fence() {
    __builtin_amdgcn_sched_barrier(0);
}

// 2-way bf16 dot with f32 accumulate: 1 VALU instr, operands already packed.
#if __has_builtin(__builtin_amdgcn_fdot2_f32_bf16)
typedef __attribute__((ext_vector_type(2))) __bf16 bf16x2_t;
__device__ __forceinline__ float dot2bf(uint a, uint b, float c) {
    return __builtin_amdgcn_fdot2_f32_bf16(__builtin_bit_cast(bf16x2_t, a),
                                           __builtin_bit_cast(bf16x2_t, b), c, false);
}
#else
__device__ __forceinline__ float dot2bf(uint a, uint b, float c) {
    return c + __uint_as_float(a << 16) * __uint_as_float(b << 16)
             + __uint_as_float(a & 0xffff0000u) * __uint_as_float(b & 0xffff0000u);
}
#endif

// ---------------------------------------------------------------- fused pre-work
__global__ void k_pre(const int* __restrict__ X, const float* __restrict__ emb,
                      bf16* __restrict__ h,
                      const float* __restrict__ qw, const float* __restrict__ kw,
                      const float* __restrict__ vw, const float* __restrict__ ow,
                      const float* __restrict__ qb, const float* __restrict__ kb,
                      const float* __restrict__ vb,
                      bf16* __restrict__ wqkv, bf16* __restrict__ wo,
                      float* __restrict__ qkvb,
                      const int* __restrict__ erow, int* __restrict__ row_ptr) {
    int b = blockIdx.x;
    if (b < 5000) {
        int tid = b * 256 + threadIdx.x;
        int n = tid >> 6;
        int c4 = (tid & 63) * 4;
        float4 a = make_float4(0.f, 0.f, 0.f, 0.f);
#pragma unroll
        for (int f = 0; f < N_FEATS; ++f) {
            int idx = X[n * N_FEATS + f];
            float4 e = *(const float4*)(emb + ((size_t)(f * VOCAB + idx)) * HIDDEN + c4);
            a.x += e.x; a.y += e.y; a.z += e.z; a.w += e.w;
        }
        ushort4 o = make_ushort4(f2u(a.x), f2u(a.y), f2u(a.z), f2u(a.w));
        *(ushort4*)((ushort*)h + (size_t)n * HIDDEN + c4) = o;
    } else if (b < 6027) {
        int i = (b - 5000) * 256 + threadIdx.x;     // 262912 total
        if (i < 196608) {
            const float* s = i < 65536 ? qw : i < 131072 ? kw : vw;
            wqkv[i] = __float2bfloat16(s[i & 65535]);
        } else if (i < 262144) {
            wo[i - 196608] = __float2bfloat16(ow[i - 196608]);
        } else if (i < 262912) {
            int j = i - 262144;                      // 768 bias elems
            const float* s = j < 256 ? qb : j < 512 ? kb : vb;
            qkvb[j] = s[j & 255];
        }
    } else {
        int n = (b - 6027) * 256 + threadIdx.x;
        if (n > N_NODES) return;
        int lo = 0, hi = N_EDGES;
        while (lo < hi) {
            int mid = (lo + hi) >> 1;
            if (erow[mid] < n) lo = mid + 1; else hi = mid;
        }
        row_ptr[n] = lo;
    }
}

// ---------------------------------------------------------------- MFMA GEMM core
// MODE 0 epilogue: K/V -> per-HEAD layout khv[h][n][64] (K 0..31 | V 32..63),
// one 128B line per (node, head).
template <int MODE, bool GUARD, int TM>
__device__ __forceinline__ void gemm_core(const bf16* __restrict__ A,
                                          const bf16* __restrict__ W,
                                          const float* __restrict__ bias,
                                          void* __restrict__ Y0, void* __restrict__ Y1,
                                          float s_q, int n0, int d0) {
    constexpr int RI = TM / 32;          // row subtiles per wave (4 or 2)
    __shared__ short As[TM * 72];
    __shared__ short Bs[128 * 72];
    int t = threadIdx.x;
    int lane = t & 63, w = t >> 6;
    int wr = (w >> 1) * (TM / 2), wc = (w & 1) * 64;
    int lr = lane & 15, quad = lane >> 4;

    f32x4 acc[RI][4] = {};
    short8 ra[RI], rb[4];
    int srowA[RI], skoA[RI], srowB[4], skoB[4];
#pragma unroll
    for (int it = 0; it < RI; ++it) { int c = t + 256 * it; srowA[it] = c >> 3; skoA[it] = (c & 7) * 8; }
#pragma unroll
    for (int it = 0; it < 4; ++it) { int c = t + 256 * it; srowB[it] = c >> 3; skoB[it] = (c & 7) * 8; }

    // prologue: load k0=0, stage to LDS
#pragma unroll
    for (int it = 0; it < RI; ++it) {
        int n = n0 + srowA[it];
        short8 av = {};
        if (!GUARD || n < N_NODES) av = *(const short8*)(A + (size_t)n * HIDDEN + skoA[it]);
        ra[it] = av;
    }
#pragma unroll
    for (int it = 0; it < 4; ++it)
        rb[it] = *(const short8*)(W + (size_t)(d0 + srowB[it]) * HIDDEN + skoB[it]);
#pragma unroll
    for (int it = 0; it < RI; ++it) *(short8*)(&As[srowA[it] * 72 + skoA[it]]) = ra[it];
#pragma unroll
    for (int it = 0; it < 4; ++it)  *(short8*)(&Bs[srowB[it] * 72 + skoB[it]]) = rb[it];
    __syncthreads();

    for (int k0 = 64; k0 < 256; k0 += 64) {
#pragma unroll
        for (int it = 0; it < RI; ++it) {
            int n = n0 + srowA[it];
            short8 av = {};
            if (!GUARD || n < N_NODES) av = *(const short8*)(A + (size_t)n * HIDDEN + k0 + skoA[it]);
            ra[it] = av;
        }
#pragma unroll
        for (int it = 0; it < 4; ++it)
            rb[it] = *(const short8*)(W + (size_t)(d0 + srowB[it]) * HIDDEN + k0 + skoB[it]);
        {
            short8 af[RI][2], bfr[4][2];
#pragma unroll
            for (int i = 0; i < RI; ++i)
#pragma unroll
                for (int kk = 0; kk < 2; ++kk)
                    af[i][kk] = *(short8*)(&As[(wr + i * 16 + lr) * 72 + kk * 32 + quad * 8]);
#pragma unroll
            for (int j = 0; j < 4; ++j)
#pragma unroll
                for (int kk = 0; kk < 2; ++kk)
                    bfr[j][kk] = *(short8*)(&Bs[(wc + j * 16 + lr) * 72 + kk * 32 + quad * 8]);
#pragma unroll
            for (int kk = 0; kk < 2; ++kk)
#pragma unroll
                for (int i = 0; i < RI; ++i)
#pragma unroll
                    for (int j = 0; j < 4; ++j)
                        acc[i][j] = __builtin_amdgcn_mfma_f32_16x16x32_bf16(
                            af[i][kk], bfr[j][kk], acc[i][j], 0, 0, 0);
        }
        __syncthreads();
#pragma unroll
        for (int it = 0; it < RI; ++it) *(short8*)(&As[srowA[it] * 72 + skoA[it]]) = ra[it];
#pragma unroll
        for (int it = 0; it < 4; ++it)  *(short8*)(&Bs[srowB[it] * 72 + skoB[it]]) = rb[it];
        __syncthreads();
    }
    {
        short8 af[RI][2], bfr[4][2];
#pragma unroll
        for (int i = 0; i < RI; ++i)
#pragma unroll
            for (int kk = 0; kk < 2; ++kk)
                af[i][kk] = *(short8*)(&As[(wr + i * 16 + lr) * 72 + kk * 32 + quad * 8]);
#pragma unroll
        for (int j = 0; j < 4; ++j)
#pragma unroll
            for (int kk = 0; kk < 2; ++kk)
                bfr[j][kk] = *(short8*)(&Bs[(wc + j * 16 + lr) * 72 + kk * 32 + quad * 8]);
#pragma unroll
        for (int kk = 0; kk < 2; ++kk)
#pragma unroll
            for (int i = 0; i < RI; ++i)
#pragma unroll
                for (int j = 0; j < 4; ++j)
                    acc[i][j] = __builtin_amdgcn_mfma_f32_16x16x32_bf16(
                        af[i][kk], bfr[j][kk], acc[i][j], 0, 0, 0);
    }

#pragma unroll
    for (int j = 0; j < 4; ++j) {
        int dbase = d0 + wc + j * 16;          // uniform
        float bj = bias[dbase + lr];
        if constexpr (MODE == 0) {
            float sc = (dbase < 256) ? s_q : 1.f;
            ushort* dst; int stride;
            if (dbase < 256) {
                dst = (ushort*)Y0 + (size_t)(dbase >> 6) * N_NODES * 64 + (dbase & 63) + lr;
                stride = 64;
            } else if (dbase < 512) {
                int e = dbase - 256;
                int head = e >> 5;
                int dim = (e & 31) + lr;
                dst = (ushort*)Y1 + (size_t)head * N_NODES * 64 + dim;
                stride = 64;
            } else {
                int e = dbase - 512;
                int head = e >> 5;
                int dim = (e & 31) + lr;
                dst = (ushort*)Y1 + (size_t)head * N_NODES * 64 + 32 + dim;
                stride = 64;
            }
#pragma unroll
            for (int i = 0; i < RI; ++i)
#pragma unroll
                for (int r = 0; r < 4; ++r) {
                    int n = n0 + wr + i * 16 + quad * 4 + r;
                    if (GUARD && n >= N_NODES) continue;
                    dst[(size_t)n * stride] = f2u((acc[i][j][r] + bj) * sc);
                }
        } else {
            float* dst = (float*)Y0 + dbase + lr;
#pragma unroll
            for (int i = 0; i < RI; ++i)
#pragma unroll
                for (int r = 0; r < 4; ++r) {
                    int n = n0 + wr + i * 16 + quad * 4 + r;
                    if (GUARD && n >= N_NODES) continue;
                    dst[(size_t)n * HIDDEN] = acc[i][j][r] + bj;
                }
        }
    }
}

__global__ __launch_bounds__(256, 2) void k_gemm_qkv(
    const bf16* __restrict__ A, const bf16* __restrict__ wqkv,
    const float* __restrict__ qkvb, ushort* __restrict__ qhp,
    ushort* __restrict__ khv, float qscale) {
    int n0 = blockIdx.x * 128;
    if (n0 + 128 <= N_NODES)
        gemm_core<0, false, 128>(A, wqkv, qkvb, qhp, khv, qscale, n0, blockIdx.y * 128);
    else
        gemm_core<0, true, 128>(A, wqkv, qkvb, qhp, khv, qscale, n0, blockIdx.y * 128);
}

__global__ __launch_bounds__(256, 4) void k_gemm_o(
    const bf16* __restrict__ A, const bf16* __restrict__ W,
    const float* __restrict__ bias, float* __restrict__ Y) {
    int n0 = blockIdx.x * 64;
    if (n0 + 64 <= N_NODES)
        gemm_core<1, false, 64>(A, W, bias, Y, nullptr, 1.f, n0, blockIdx.y * 128);
    else
        gemm_core<1, true, 64>(A, W, bias, Y, nullptr, 1.f, n0, blockIdx.y * 128);
}

// ---------------------------------------------------------------- fused attention
// R28: khv per-head layout (R14: L2-resident, FETCH 100->31MB) + PAIRED nodes.
// R14's regression was unit-count doubling (160k units, fixed overhead ~dominant).
// Now each wave handles TWO nodes of the SAME head: lane bit5 = node, each
// 32-lane half = 8 edge-slots x 4 dim-chunks. Every load/score/PV instruction
// serves both units; fixed costs (z-reduce 3 stages, combine 3 stages, store,
// addressing) are per-wave -> halved per unit. Same-head pairing keeps ONE
// 2.56MB slice per XCD (residency preserved; R10's cross-hp thrash doesn't
// apply). NIT = ceil(max(degA,degB)/8). 80k wave-units, 20000 blocks.

// PV accumulate: 8 dims per lane (d4*8..+7), unpack bf16 pairs + packed FMA.
template <int NIT>
__device__ __forceinline__ void pv_accum(const uint4* vv, const float* pb,
                                         f32x2& av0, f32x2& av1, f32x2& av2v, f32x2& av3) {
#pragma unroll
    for (int it = 0; it < NIT; ++it) {
        f32x2 pp; pp.x = pb[it]; pp.y = pb[it];
        f32x2 vf0, vf1, vf2, vf3;
        vf0.x = __uint_as_float(vv[it].x << 16); vf0.y = __uint_as_float(vv[it].x & 0xffff0000u);
        vf1.x = __uint_as_float(vv[it].y << 16); vf1.y = __uint_as_float(vv[it].y & 0xffff0000u);
        vf2.x = __uint_as_float(vv[it].z << 16); vf2.y = __uint_as_float(vv[it].z & 0xffff0000u);
        vf3.x = __uint_as_float(vv[it].w << 16); vf3.y = __uint_as_float(vv[it].w & 0xffff0000u);
        av0  = pk_fma(vf0, pp, av0);
        av1  = pk_fma(vf1, pp, av1);
        av2v = pk_fma(vf2, pp, av2v);
        av3  = pk_fma(vf3, pp, av3);
    }
}

// paired dense: NIT*8 edge slots per node-half; one kv line per (edge,head).
template <int NIT>
__device__ __forceinline__ void attn_pair(const int* __restrict__ col,
                                          int start, int deg,   // per-lane (half)
                                          int lane, int my, int d4, int n,
                                          const ushort* __restrict__ qhp,
                                          const ushort* __restrict__ khbase,
                                          int h, ushort* __restrict__ agg16) {
    int degm = deg - my;                  // edge it*8+my valid iff it*8 < degm
    uint d4b = (uint)d4 * 8;

    int cc[NIT];
#pragma unroll
    for (int it = 0; it < NIT; ++it) {
        int idx = min(it * 8 + my, deg - 1);
        idx = max(idx, 0);
        cc[it] = col[min(start + idx, N_EDGES - 1)];
    }

    const ushort* qrow = qhp + ((size_t)(h >> 1) * N_NODES + n) * 64 + (h & 1) * 32;
    uint4 qu = *(const uint4*)(qrow + d4b);
    uint4 kk[NIT], vv[NIT];
#pragma unroll
    for (int it = 0; it < NIT; ++it)          // K first: scores drain vmcnt early
        kk[it] = *(const uint4*)(khbase + (((size_t)(uint)cc[it]) << 6) + d4b);
#pragma unroll
    for (int it = 0; it < NIT; ++it)          // V: same lines, cache hits
        vv[it] = *(const uint4*)(khbase + (((size_t)(uint)cc[it]) << 6) + 32 + d4b);

    sched_fence();                            // all loads issued before compute

    float z = 0.f;
    float pb[NIT];
#pragma unroll
    for (int it = 0; it < NIT; ++it) {
        float s = dot2bf(kk[it].x, qu.x, 0.f);
        s = dot2bf(kk[it].y, qu.y, s);
        s = dot2bf(kk[it].z, qu.z, s);
        s = dot2bf(kk[it].w, qu.w, s);
        s += dpp_xor<0xB1>(s);                // quad reduce over d4 bits 0,1:
        s += dpp_xor<0x4E>(s);                // full 32-dim score
        float p = (it * 8 < degm) ? fast_exp2(s) : 0.f;
        z += p;
        pb[it] = p;                           // p already in the right PV lane
    }
    // z over this half's 8 slots: ror4+ror8 (row sum) + xor16 (stays in half)
    z += dpp_xor<0x124>(z);
    z += dpp_xor<0x128>(z);
    z += __shfl_xor(z, 16);

    f32x2 av0 = {0.f, 0.f}, av1 = {0.f, 0.f}, av2v = {0.f, 0.f}, av3 = {0.f, 0.f};
    pv_accum<NIT>(vv, pb, av0, av1, av2v, av3);

    // combine over slot bits 2..4 (in-half); every lane stores one dim
    bool b2 = (lane & 4) != 0, b3 = (lane & 8) != 0, b4 = (lane & 16) != 0;
    f32x2 sd0 = b2 ? av0 : av2v;
    f32x2 sd1 = b2 ? av1 : av3;
    f32x2 r0, r1;
    r0.x = __shfl_xor(sd0.x, 4); r0.y = __shfl_xor(sd0.y, 4);
    r1.x = __shfl_xor(sd1.x, 4); r1.y = __shfl_xor(sd1.y, 4);
    f32x2 t0 = pk_add(b2 ? av2v : av0, r0);
    f32x2 t1 = pk_add(b2 ? av3  : av1, r1);
    f32x2 sdu = b3 ? t0 : t1;
    f32x2 ru; ru.x = __shfl_xor(sdu.x, 8); ru.y = __shfl_xor(sdu.y, 8);
    f32x2 u = pk_add(b3 ? t1 : t0, ru);
    float sw = b4 ? u.x : u.y;
    float rw = __shfl_xor(sw, 16);
    float w = (b4 ? u.y : u.x) + rw;          // dim = d4*8+b2*4+b3*2+b4

    float invz = z > 0.f ? 1.f / z : 0.f;     // deg==0 half -> exact 0 output
    int dim = d4 * 8 + ((lane >> 2) & 1) * 4 + ((lane >> 3) & 1) * 2 + ((lane >> 4) & 1);
    agg16[(size_t)n * HIDDEN + h * 32 + dim] = f2u(w * invz);
}

// fallback (deg > 64, ~never): full-wave 16 slots x 4 dims for one node.
__device__ __forceinline__ void attn_fallback(const int* __restrict__ cb, int deg,
                                              int lane, const ushort* __restrict__ qrow,
                                              const ushort* __restrict__ khbase,
                                              ushort* __restrict__ orow) {
    int my = lane >> 2;
    int d4 = lane & 3;
    uint d4b = (uint)d4 * 8;
    uint4 qu = *(const uint4*)(qrow + d4b);
    float z = 0.f;
    f32x2 av0 = {0.f, 0.f}, av1 = {0.f, 0.f}, av2v = {0.f, 0.f}, av3 = {0.f, 0.f};
    for (int i = 0; i < deg; i += 16) {
        int idx = i + my;
        int c = cb[min(idx, deg - 1)];
        const ushort* kp = khbase + (((size_t)(uint)c) << 6) + d4b;
        uint4 ku = *(const uint4*)(kp);
        uint4 vu = *(const uint4*)(kp + 32);
        float s = dot2bf(ku.x, qu.x, 0.f);
        s = dot2bf(ku.y, qu.y, s);
        s = dot2bf(ku.z, qu.z, s);
        s = dot2bf(ku.w, qu.w, s);
        s += dpp_xor<0xB1>(s);
        s += dpp_xor<0x4E>(s);
        float p = (idx < deg) ? fast_exp2(s) : 0.f;
        z += p;
        f32x2 pp; pp.x = p; pp.y = p;
        f32x2 vf0, vf1, vf2, vf3;
        vf0.x = __uint_as_float(vu.x << 16); vf0.y = __uint_as_float(vu.x & 0xffff0000u);
        vf1.x = __uint_as_float(vu.y << 16); vf1.y = __uint_as_float(vu.y & 0xffff0000u);
        vf2.x = __uint_as_float(vu.z << 16); vf2.y = __uint_as_float(vu.z & 0xffff0000u);
        vf3.x = __uint_as_float(vu.w << 16); vf3.y = __uint_as_float(vu.w & 0xffff0000u);
        av0  = pk_fma(vf0, pp, av0);
        av1  = pk_fma(vf1, pp, av1);
        av2v = pk_fma(vf2, pp, av2v);
        av3  = pk_fma(vf3, pp, av3);
    }
    z += dpp_xor<0x124>(z);
    z += dpp_xor<0x128>(z);
    z += __shfl_xor(z, 16);
    z += __shfl_xor(z, 32);
    // combine over slot bits 2..5, fold, lanes<32 store
    bool b2 = (lane & 4) != 0, b3 = (lane & 8) != 0, b4 = (lane & 16) != 0;
    f32x2 sd0 = b2 ? av0 : av2v;
    f32x2 sd1 = b2 ? av1 : av3;
    f32x2 r0, r1;
    r0.x = __shfl_xor(sd0.x, 4); r0.y = __shfl_xor(sd0.y, 4);
    r1.x = __shfl_xor(sd1.x, 4); r1.y = __shfl_xor(sd1.y, 4);
    f32x2 t0 = pk_add(b2 ? av2v : av0, r0);
    f32x2 t1 = pk_add(b2 ? av3  : av1, r1);
    f32x2 sdu = b3 ? t0 : t1;
    f32x2 ru; ru.x = __shfl_xor(sdu.x, 8); ru.y = __shfl_xor(sdu.y, 8);
    f32x2 u = pk_add(b3 ? t1 : t0, ru);
    float sw = b4 ? u.x : u.y;
    float rw = __shfl_xor(sw, 16);
    float w = (b4 ? u.y : u.x) + rw;
    w += __shfl_xor(w, 32);
    if (lane < 32) {
        int dim = d4 * 8 + ((lane >> 2) & 1) * 4 + ((lane >> 3) & 1) * 2 + ((lane >> 4) & 1);
        orow[dim] = f2u(w * (1.f / z));
    }
}

__global__ __launch_bounds__(256, 4) void k_attn(
    const int* __restrict__ row_ptr, const int* __restrict__ col,
    const ushort* __restrict__ qhp, const ushort* __restrict__ khv,
    bf16* __restrict__ agg) {
    int b = blockIdx.x;          // 20000 blocks
    int h = b & 7;               // head = XCD (b%8): one 2.56MB slice per XCD
    // wave-uniform: lets the compiler scalarize base addrs
    int wave = __builtin_amdgcn_readfirstlane((int)(threadIdx.x >> 6));
    int nA = ((b >> 3) * 4 + wave) * 2;      // pair base node
    int lane = threadIdx.x & 63;
    int nodeb = lane >> 5;       // 0 = node A half, 1 = node B half
    int my = (lane >> 2) & 7;    // edge slot 0..7 within half
    int d4 = lane & 3;           // dim chunk (8 dims)
    int n = nA + nodeb;

    int start = row_ptr[n];
    int deg = row_ptr[n + 1] - start;

    const ushort* khbase = khv + (size_t)h * N_NODES * 64;
    ushort* agg16 = (ushort*)agg;

    // uniform max degree decides the template instance
    int degA = __shfl(deg, 0);
    int degB = __shfl(deg, 32);
    int mx = max(degA, degB);

    if (mx <= 16)      attn_pair<2>(col, start, deg, lane, my, d4, n, qhp, khbase, h, agg16);
    else if (mx <= 24) attn_pair<3>(col, start, deg, lane, my, d4, n, qhp, khbase, h, agg16);
    else if (mx <= 32) attn_pair<4>(col, start, deg, lane, my, d4, n, qhp, khbase, h, agg16);
    else if (mx <= 40) attn_pair<5>(col, start, deg, lane, my, d4, n, qhp, khbase, h, agg16);
    else if (mx <= 48) attn_pair<6>(col, start, deg, lane, my, d4, n, qhp, khbase, h, agg16);
    else if (mx <= 64) attn_pair<8>(col, start, deg, lane, my, d4, n, qhp, khbase, h, agg16);
    else {
        // rare: full-wave fallback per node
#pragma unroll 1
        for (int v = 0; v < 2; ++v) {
            int nn = nA + v;
            int s0 = __shfl(start, v * 32);
            int d0 = v ? degB : degA;
            ushort* orow = agg16 + (size_t)nn * HIDDEN + h * 32;
            if (d0 == 0) {
                if (lane < 4) { uint4 zo = {}; *(uint4*)(orow + lane * 8) = zo; }
                continue;
            }
            const ushort* qrow = qhp + ((size_t)(h >> 1) * N_NODES + nn) * 64 + (h & 1) * 32;
            attn_fallback(col + s0, d0, lane, qrow, khbase, orow);
        }
    }
}

// ---------------------------------------------------------------- launch
extern "C" void kernel_launch(void* const* d_in, const int* in_sizes, int n_in,
                              void* d_out, int out_size, void* d_ws, size_t ws_size,
                              hipStream_t stream) {
    const int*   X    = (const int*)d_in[0];
    const int*   erow = (const int*)d_in[1];
    const int*   ecol = (const int*)d_in[2];
    const float* emb  = (const float*)d_in[3];
    const float* q_w  = (const float*)d_in[4];
    const float* q_b  = (const float*)d_in[5];
    const float* k_w  = (const float*)d_in[6];
    const float* k_b  = (const float*)d_in[7];
    const float* v_w  = (const float*)d_in[8];
    const float* v_b  = (const float*)d_in[9];
    const float* o_w  = (const float*)d_in[10];
    const float* o_b  = (const float*)d_in[11];
    float* out = (float*)d_out;

    char* ws = (char*)d_ws;
    bf16*   h    = (bf16*)(ws);
    bf16*   agg  = (bf16*)(ws);                 // aliases h (dead after QKV GEMM)
    ushort* qhp  = (ushort*)(ws + 10240000);
    ushort* khv  = (ushort*)(ws + 20480000);    // [8 heads][N][64] = 20.48MB
    bf16*   wqkv = (bf16*)(ws + 40960000);
    bf16*   wo   = (bf16*)(ws + 41353216);
    float*  qkvb = (float*)(ws + 41484288);
    int* row_ptr = (int*)(ws + 41487360);

    k_pre<<<6106, 256, 0, stream>>>(X, emb, h, q_w, k_w, v_w, o_w,
                                    q_b, k_b, v_b, wqkv, wo, qkvb, erow, row_ptr);

    // 1/sqrt(32) * log2(e): scores in log2 domain -> raw v_exp_f32 in k_attn.
    const float qscale = 0.25503486121587466f;
    dim3 gqkv((N_NODES + 127) / 128, 768 / 128);
    k_gemm_qkv<<<gqkv, 256, 0, stream>>>(h, wqkv, qkvb, qhp, khv, qscale);

    k_attn<<<20000, 256, 0, stream>>>(row_ptr, ecol, qhp, khv, agg);

    dim3 go((N_NODES + 63) / 64, HIDDEN / 128);
    k_gemm_o<<<go, 256, 0, stream>>>(agg, wo, o_b, out);
}

// Round 16
// 172.233 us; speedup vs baseline: 1.0484x; 1.0484x over previous
//
#include <hip/hip_runtime.h>
#include <hip/hip_bf16.h>

#define N_NODES 20000
#define N_EDGES 640000
#define HIDDEN 256
#define HEADS 8
#define HEAD_DIM 32
#define N_FEATS 9
#define VOCAB 119

typedef __hip_bfloat16 bf16;
typedef __attribute__((ext_vector_type(8))) short short8;
typedef __attribute__((ext_vector_type(4))) float f32x4;
typedef __attribute__((ext_vector_type(2))) float f32x2;

__device__ __forceinline__ ushort f2u(float x) { union { ushort u; bf16 b; } c; c.b = __float2bfloat16(x); return c.u; }

// packed f32 math (CDNA: full-rate 2x FMA per instr)
__device__ __forceinline__ f32x2 pk_fma(f32x2 a, f32x2 b, f32x2 c) {
    f32x2 d;
    asm("v_pk_fma_f32 %0, %1, %2, %3" : "=v"(d) : "v"(a), "v"(b), "v"(c));
    return d;
}
__device__ __forceinline__ f32x2 pk_add(f32x2 a, f32x2 b) {
    f32x2 d;
    asm("v_pk_add_f32 %0, %1, %2" : "=v"(d) : "v"(a), "v"(b));
    return d;
}

// DPP cross-lane fetch (VALU pipe, no ds_bpermute latency).
// 0xB1 = quad_perm xor1, 0x4E = quad_perm xor2, 0x128 = row_ror:8 (== xor 8
// within a 16-lane row for reduction purposes).
template <int CTRL>
__device__ __forceinline__ float dpp_xor(float v) {
    return __int_as_float(__builtin_amdgcn_update_dpp(
        0, __float_as_int(v), CTRL, 0xf, 0xf, true));
}

__device__ __forceinline__ float fast_exp2(float x) {
#if __has_builtin(__builtin_amdgcn_exp2f)
    return __builtin_amdgcn_exp2f(x);
#else
    return exp2f(x);
#endif
}

// hard scheduling fence: nothing moves across (pins "issue all loads, then
// compute"). ONLY safe at the end of a wave's work — R7 showed that inside a
// loop it serializes iterations.
__device__ __forceinline__ void sched_fence() {
    __builtin_amdgcn_sched_barrier(0);
}

// 2-way bf16 dot with f32 accumulate: 1 VALU instr, operands already packed.
#if __has_builtin(__builtin_amdgcn_fdot2_f32_bf16)
typedef __attribute__((ext_vector_type(2))) __bf16 bf16x2_t;
__device__ __forceinline__ float dot2bf(uint a, uint b, float c) {
    return __builtin_amdgcn_fdot2_f32_bf16(__builtin_bit_cast(bf16x2_t, a),
                                           __builtin_bit_cast(bf16x2_t, b), c, false);
}
#else
__device__ __forceinline__ float dot2bf(uint a, uint b, float c) {
    return c + __uint_as_float(a << 16) * __uint_as_float(b << 16)
             + __uint_as_float(a & 0xffff0000u) * __uint_as_float(b & 0xffff0000u);
}
#endif

// ---------------------------------------------------------------- fused pre-work
__global__ void k_pre(const int* __restrict__ X, const float* __restrict__ emb,
                      bf16* __restrict__ h,
                      const float* __restrict__ qw, const float* __restrict__ kw,
                      const float* __restrict__ vw, const float* __restrict__ ow,
                      const float* __restrict__ qb, const float* __restrict__ kb,
                      const float* __restrict__ vb,
                      bf16* __restrict__ wqkv, bf16* __restrict__ wo,
                      float* __restrict__ qkvb,
                      const int* __restrict__ erow, int* __restrict__ row_ptr) {
    int b = blockIdx.x;
    if (b < 5000) {
        int tid = b * 256 + threadIdx.x;
        int n = tid >> 6;
        int c4 = (tid & 63) * 4;
        float4 a = make_float4(0.f, 0.f, 0.f, 0.f);
#pragma unroll
        for (int f = 0; f < N_FEATS; ++f) {
            int idx = X[n * N_FEATS + f];
            float4 e = *(const float4*)(emb + ((size_t)(f * VOCAB + idx)) * HIDDEN + c4);
            a.x += e.x; a.y += e.y; a.z += e.z; a.w += e.w;
        }
        ushort4 o = make_ushort4(f2u(a.x), f2u(a.y), f2u(a.z), f2u(a.w));
        *(ushort4*)((ushort*)h + (size_t)n * HIDDEN + c4) = o;
    } else if (b < 6027) {
        int i = (b - 5000) * 256 + threadIdx.x;     // 262912 total
        if (i < 196608) {
            const float* s = i < 65536 ? qw : i < 131072 ? kw : vw;
            wqkv[i] = __float2bfloat16(s[i & 65535]);
        } else if (i < 262144) {
            wo[i - 196608] = __float2bfloat16(ow[i - 196608]);
        } else if (i < 262912) {
            int j = i - 262144;                      // 768 bias elems
            const float* s = j < 256 ? qb : j < 512 ? kb : vb;
            qkvb[j] = s[j & 255];
        }
    } else {
        int n = (b - 6027) * 256 + threadIdx.x;
        if (n > N_NODES) return;
        int lo = 0, hi = N_EDGES;
        while (lo < hi) {
            int mid = (lo + hi) >> 1;
            if (erow[mid] < n) lo = mid + 1; else hi = mid;
        }
        row_ptr[n] = lo;
    }
}

// ---------------------------------------------------------------- MFMA GEMM core
template <int MODE, bool GUARD, int TM>
__device__ __forceinline__ void gemm_core(const bf16* __restrict__ A,
                                          const bf16* __restrict__ W,
                                          const float* __restrict__ bias,
                                          void* __restrict__ Y0, void* __restrict__ Y1,
                                          float s_q, int n0, int d0) {
    constexpr int RI = TM / 32;          // row subtiles per wave (4 or 2)
    __shared__ short As[TM * 72];
    __shared__ short Bs[128 * 72];
    int t = threadIdx.x;
    int lane = t & 63, w = t >> 6;
    int wr = (w >> 1) * (TM / 2), wc = (w & 1) * 64;
    int lr = lane & 15, quad = lane >> 4;

    f32x4 acc[RI][4] = {};
    short8 ra[RI], rb[4];
    int srowA[RI], skoA[RI], srowB[4], skoB[4];
#pragma unroll
    for (int it = 0; it < RI; ++it) { int c = t + 256 * it; srowA[it] = c >> 3; skoA[it] = (c & 7) * 8; }
#pragma unroll
    for (int it = 0; it < 4; ++it) { int c = t + 256 * it; srowB[it] = c >> 3; skoB[it] = (c & 7) * 8; }

    // prologue: load k0=0, stage to LDS
#pragma unroll
    for (int it = 0; it < RI; ++it) {
        int n = n0 + srowA[it];
        short8 av = {};
        if (!GUARD || n < N_NODES) av = *(const short8*)(A + (size_t)n * HIDDEN + skoA[it]);
        ra[it] = av;
    }
#pragma unroll
    for (int it = 0; it < 4; ++it)
        rb[it] = *(const short8*)(W + (size_t)(d0 + srowB[it]) * HIDDEN + skoB[it]);
#pragma unroll
    for (int it = 0; it < RI; ++it) *(short8*)(&As[srowA[it] * 72 + skoA[it]]) = ra[it];
#pragma unroll
    for (int it = 0; it < 4; ++it)  *(short8*)(&Bs[srowB[it] * 72 + skoB[it]]) = rb[it];
    __syncthreads();

    for (int k0 = 64; k0 < 256; k0 += 64) {
#pragma unroll
        for (int it = 0; it < RI; ++it) {
            int n = n0 + srowA[it];
            short8 av = {};
            if (!GUARD || n < N_NODES) av = *(const short8*)(A + (size_t)n * HIDDEN + k0 + skoA[it]);
            ra[it] = av;
        }
#pragma unroll
        for (int it = 0; it < 4; ++it)
            rb[it] = *(const short8*)(W + (size_t)(d0 + srowB[it]) * HIDDEN + k0 + skoB[it]);
        {
            short8 af[RI][2], bfr[4][2];
#pragma unroll
            for (int i = 0; i < RI; ++i)
#pragma unroll
                for (int kk = 0; kk < 2; ++kk)
                    af[i][kk] = *(short8*)(&As[(wr + i * 16 + lr) * 72 + kk * 32 + quad * 8]);
#pragma unroll
            for (int j = 0; j < 4; ++j)
#pragma unroll
                for (int kk = 0; kk < 2; ++kk)
                    bfr[j][kk] = *(short8*)(&Bs[(wc + j * 16 + lr) * 72 + kk * 32 + quad * 8]);
#pragma unroll
            for (int kk = 0; kk < 2; ++kk)
#pragma unroll
                for (int i = 0; i < RI; ++i)
#pragma unroll
                    for (int j = 0; j < 4; ++j)
                        acc[i][j] = __builtin_amdgcn_mfma_f32_16x16x32_bf16(
                            af[i][kk], bfr[j][kk], acc[i][j], 0, 0, 0);
        }
        __syncthreads();
#pragma unroll
        for (int it = 0; it < RI; ++it) *(short8*)(&As[srowA[it] * 72 + skoA[it]]) = ra[it];
#pragma unroll
        for (int it = 0; it < 4; ++it)  *(short8*)(&Bs[srowB[it] * 72 + skoB[it]]) = rb[it];
        __syncthreads();
    }
    {
        short8 af[RI][2], bfr[4][2];
#pragma unroll
        for (int i = 0; i < RI; ++i)
#pragma unroll
            for (int kk = 0; kk < 2; ++kk)
                af[i][kk] = *(short8*)(&As[(wr + i * 16 + lr) * 72 + kk * 32 + quad * 8]);
#pragma unroll
        for (int j = 0; j < 4; ++j)
#pragma unroll
            for (int kk = 0; kk < 2; ++kk)
                bfr[j][kk] = *(short8*)(&Bs[(wc + j * 16 + lr) * 72 + kk * 32 + quad * 8]);
#pragma unroll
        for (int kk = 0; kk < 2; ++kk)
#pragma unroll
            for (int i = 0; i < RI; ++i)
#pragma unroll
                for (int j = 0; j < 4; ++j)
                    acc[i][j] = __builtin_amdgcn_mfma_f32_16x16x32_bf16(
                        af[i][kk], bfr[j][kk], acc[i][j], 0, 0, 0);
    }

#pragma unroll
    for (int j = 0; j < 4; ++j) {
        int dbase = d0 + wc + j * 16;          // uniform
        float bj = bias[dbase + lr];
        if constexpr (MODE == 0) {
            float sc = (dbase < 256) ? s_q : 1.f;
            ushort* dst; int stride;
            if (dbase < 256) {
                dst = (ushort*)Y0 + (size_t)(dbase >> 6) * N_NODES * 64 + (dbase & 63) + lr;
                stride = 64;
            } else if (dbase < 512) {
                int e = dbase - 256;
                dst = (ushort*)Y1 + (size_t)(e >> 6) * N_NODES * 128 + (e & 63) + lr;
                stride = 128;
            } else {
                int e = dbase - 512;
                dst = (ushort*)Y1 + (size_t)(e >> 6) * N_NODES * 128 + 64 + (e & 63) + lr;
                stride = 128;
            }
#pragma unroll
            for (int i = 0; i < RI; ++i)
#pragma unroll
                for (int r = 0; r < 4; ++r) {
                    int n = n0 + wr + i * 16 + quad * 4 + r;
                    if (GUARD && n >= N_NODES) continue;
                    dst[(size_t)n * stride] = f2u((acc[i][j][r] + bj) * sc);
                }
        } else {
            float* dst = (float*)Y0 + dbase + lr;
#pragma unroll
            for (int i = 0; i < RI; ++i)
#pragma unroll
                for (int r = 0; r < 4; ++r) {
                    int n = n0 + wr + i * 16 + quad * 4 + r;
                    if (GUARD && n >= N_NODES) continue;
                    dst[(size_t)n * HIDDEN] = acc[i][j][r] + bj;
                }
        }
    }
}

__global__ __launch_bounds__(256, 2) void k_gemm_qkv(
    const bf16* __restrict__ A, const bf16* __restrict__ wqkv,
    const float* __restrict__ qkvb, ushort* __restrict__ qhp,
    ushort* __restrict__ kvhp, float qscale) {
    int n0 = blockIdx.x * 128;
    if (n0 + 128 <= N_NODES)
        gemm_core<0, false, 128>(A, wqkv, qkvb, qhp, kvhp, qscale, n0, blockIdx.y * 128);
    else
        gemm_core<0, true, 128>(A, wqkv, qkvb, qhp, kvhp, qscale, n0, blockIdx.y * 128);
}

__global__ __launch_bounds__(256, 4) void k_gemm_o(
    const bf16* __restrict__ A, const bf16* __restrict__ W,
    const float* __restrict__ bias, float* __restrict__ Y) {
    int n0 = blockIdx.x * 64;
    if (n0 + 64 <= N_NODES)
        gemm_core<1, false, 64>(A, W, bias, Y, nullptr, 1.f, n0, blockIdx.y * 128);
    else
        gemm_core<1, true, 64>(A, W, bias, Y, nullptr, 1.f, n0, blockIdx.y * 128);
}

// ---------------------------------------------------------------- fused attention
// FINAL (R30) = session champion: R8 structure + R13 NIT ladder.
// Operating point (verified): k_attn ~47us, VALUBusy ~51%, occ ~45%, FETCH
// ~100MB, VGPR 44. Structures refuted with counters: persistent loop (R7),
// cross-hp pairing (R10, L2 thrash), 1024-thr blocks (R11), per-head split
// (R14, unit doubling), per-head+node-pairing (R15, overhead = savings).
// R14/R15 proved FETCH can drop to 31MB with NO dur gain -> the kernel sits
// at a latency equilibrium invariant to both traffic and instruction count.
// Kept: transaction-optimal (my,d8) layout, direct col loads, K before V,
// one end-of-work fence, batched loads, degree-graded NIT.

// PV accumulate: dims d8*8..+7, unpack bf16 pairs + packed FMA.
template <int NIT>
__device__ __forceinline__ void pv_accum(const uint4* vv, const float* pb,
                                         f32x2& av0, f32x2& av1, f32x2& av2v, f32x2& av3) {
#pragma unroll
    for (int it = 0; it < NIT; ++it) {
        f32x2 pp; pp.x = pb[it]; pp.y = pb[it];
        f32x2 vf0, vf1, vf2, vf3;
        vf0.x = __uint_as_float(vv[it].x << 16); vf0.y = __uint_as_float(vv[it].x & 0xffff0000u);
        vf1.x = __uint_as_float(vv[it].y << 16); vf1.y = __uint_as_float(vv[it].y & 0xffff0000u);
        vf2.x = __uint_as_float(vv[it].z << 16); vf2.y = __uint_as_float(vv[it].z & 0xffff0000u);
        vf3.x = __uint_as_float(vv[it].w << 16); vf3.y = __uint_as_float(vv[it].w & 0xffff0000u);
        av0  = pk_fma(vf0, pp, av0);
        av1  = pk_fma(vf1, pp, av1);
        av2v = pk_fma(vf2, pp, av2v);
        av3  = pk_fma(vf3, pp, av3);
    }
}

// reduce-scatter combine over edge-slot bits 3..5; lane stores dim
// d8*8 + b3*4 + b4*2 + b5.
__device__ __forceinline__ void attn_combine(int lane, int d8, float z,
                                             f32x2 av0, f32x2 av1, f32x2 av2v, f32x2 av3,
                                             ushort* __restrict__ orow) {
    bool b3 = (lane & 8) != 0, b4 = (lane & 16) != 0, b5 = (lane & 32) != 0;
    f32x2 sd0 = b3 ? av0 : av2v;
    f32x2 sd1 = b3 ? av1 : av3;
    f32x2 r0, r1;
    r0.x = dpp_xor<0x128>(sd0.x); r0.y = dpp_xor<0x128>(sd0.y);
    r1.x = dpp_xor<0x128>(sd1.x); r1.y = dpp_xor<0x128>(sd1.y);
    f32x2 t0 = pk_add(b3 ? av2v : av0, r0);
    f32x2 t1 = pk_add(b3 ? av3  : av1, r1);
    f32x2 sdu = b4 ? t0 : t1;
    f32x2 ru; ru.x = __shfl_xor(sdu.x, 16); ru.y = __shfl_xor(sdu.y, 16);
    f32x2 u = pk_add(b4 ? t1 : t0, ru);
    float sw = b5 ? u.x : u.y;
    float rw = __shfl_xor(sw, 32);
    float w = (b5 ? u.y : u.x) + rw;
    int dim = d8 * 8 + ((lane >> 3) & 1) * 4 + ((lane >> 4) & 1) * 2 + ((lane >> 5) & 1);
    orow[dim] = f2u(w * (1.f / z));
}

// one-shot dense path: NIT*8 edge slots, all K/V lines touched exactly once.
template <int NIT>
__device__ __forceinline__ void attn_dense(const int* __restrict__ cb, int deg,
                                           int lane, int my, int d8,
                                           const ushort* __restrict__ qrow,
                                           const ushort* __restrict__ kvbase,
                                           ushort* __restrict__ orow) {
    int degm8 = deg - my;                 // edge it*8+my valid iff it*8 < degm8
    uint d8b = (uint)d8 * 8;

    // direct col loads: all NIT hit the same 1-2 cache lines (deg<=64)
    int cc[NIT];
#pragma unroll
    for (int it = 0; it < NIT; ++it) cc[it] = cb[min(it * 8 + my, deg - 1)];

    uint4 qu = *(const uint4*)(qrow + d8b);
    uint4 kk[NIT], vv[NIT];
#pragma unroll
    for (int it = 0; it < NIT; ++it)          // K first: scores drain vmcnt early
        kk[it] = *(const uint4*)(kvbase + (((size_t)(uint)cc[it]) << 7) + d8b);
#pragma unroll
    for (int it = 0; it < NIT; ++it)          // V stays in flight during scores
        vv[it] = *(const uint4*)(kvbase + (((size_t)(uint)cc[it]) << 7) + 64 + d8b);

    sched_fence();                            // all loads issued before compute

    float z = 0.f;
    float pb[NIT];
#pragma unroll
    for (int it = 0; it < NIT; ++it) {
        float s = dot2bf(kk[it].x, qu.x, 0.f);
        s = dot2bf(kk[it].y, qu.y, s);
        s = dot2bf(kk[it].z, qu.z, s);
        s = dot2bf(kk[it].w, qu.w, s);
        s += dpp_xor<0xB1>(s);                // quad reduce over d8 bits 0,1:
        s += dpp_xor<0x4E>(s);                // full 32-dim score for head d8>>2
        float p = (it * 8 < degm8) ? fast_exp2(s) : 0.f;
        z += p;
        pb[it] = p;                           // p already in the right PV lane
    }
    z += dpp_xor<0x128>(z);                   // reduce over edge-slot bits 3..5
    z += __shfl_xor(z, 16);
    z += __shfl_xor(z, 32);

    f32x2 av0 = {0.f, 0.f}, av1 = {0.f, 0.f}, av2v = {0.f, 0.f}, av3 = {0.f, 0.f};
    pv_accum<NIT>(vv, pb, av0, av1, av2v, av3);
    attn_combine(lane, d8, z, av0, av1, av2v, av3, orow);
}

__global__ __launch_bounds__(256, 4) void k_attn(
    const int* __restrict__ row_ptr, const int* __restrict__ col,
    const ushort* __restrict__ qhp, const ushort* __restrict__ kvhp,
    bf16* __restrict__ agg) {
    int b = blockIdx.x;
    int x = b & 7;
    int hp = x & 3;
    // wave-uniform: lets the compiler scalarize row_ptr loads + base addrs
    int wave = __builtin_amdgcn_readfirstlane((int)(threadIdx.x >> 6));
    int n = (b >> 3) * 8 + (x >> 2) * 4 + wave;
    int lane = threadIdx.x & 63;
    int my = lane >> 3;          // edge slot 0..7
    int d8 = lane & 7;           // dim chunk (head = d8>>2)

    int start = row_ptr[n];
    int deg = row_ptr[n + 1] - start;

    ushort* orow = (ushort*)agg + (size_t)n * HIDDEN + hp * 64;
    if (deg == 0) {
        if (lane < 8) { uint4 zo = {}; *(uint4*)(orow + lane * 8) = zo; }
        return;
    }

    const ushort* qrow = qhp + ((size_t)hp * N_NODES + n) * 64;   // log2e pre-scaled
    const ushort* kvbase = kvhp + (size_t)hp * N_NODES * 128;
    const int* cb = col + start;

    // degree-graded NIT ladder (wave-uniform branches, NIT = ceil(deg/8))
    if (deg <= 32) {
        if (deg <= 24) attn_dense<3>(cb, deg, lane, my, d8, qrow, kvbase, orow);
        else           attn_dense<4>(cb, deg, lane, my, d8, qrow, kvbase, orow);
    } else if (deg <= 64) {
        if (deg <= 40)      attn_dense<5>(cb, deg, lane, my, d8, qrow, kvbase, orow);
        else if (deg <= 48) attn_dense<6>(cb, deg, lane, my, d8, qrow, kvbase, orow);
        else if (deg <= 56) attn_dense<7>(cb, deg, lane, my, d8, qrow, kvbase, orow);
        else                attn_dense<8>(cb, deg, lane, my, d8, qrow, kvbase, orow);
    } else {
        // ---- fallback deg > 64 (Poisson(32): ~never) : dim-parallel loop ----
        uint4 qu = *(const uint4*)(qrow + d8 * 8);
        float z = 0.f;
        f32x2 av0 = {0.f, 0.f}, av1 = {0.f, 0.f}, av2v = {0.f, 0.f}, av3 = {0.f, 0.f};
        for (int i = 0; i < deg; i += 8) {
            int idx = i + my;
            int cidx = idx < deg ? idx : deg - 1;
            int c = cb[cidx];
            const ushort* kp = kvbase + (((size_t)(uint)c) << 7) + (uint)d8 * 8;
            uint4 ku = *(const uint4*)(kp);
            uint4 vu = *(const uint4*)(kp + 64);
            float s = dot2bf(ku.x, qu.x, 0.f);
            s = dot2bf(ku.y, qu.y, s);
            s = dot2bf(ku.z, qu.z, s);
            s = dot2bf(ku.w, qu.w, s);
            s += dpp_xor<0xB1>(s);
            s += dpp_xor<0x4E>(s);
            float p = (idx < deg) ? fast_exp2(s) : 0.f;
            z += p;
            f32x2 pp; pp.x = p; pp.y = p;
            f32x2 vf0, vf1, vf2, vf3;
            vf0.x = __uint_as_float(vu.x << 16); vf0.y = __uint_as_float(vu.x & 0xffff0000u);
            vf1.x = __uint_as_float(vu.y << 16); vf1.y = __uint_as_float(vu.y & 0xffff0000u);
            vf2.x = __uint_as_float(vu.z << 16); vf2.y = __uint_as_float(vu.z & 0xffff0000u);
            vf3.x = __uint_as_float(vu.w << 16); vf3.y = __uint_as_float(vu.w & 0xffff0000u);
            av0  = pk_fma(vf0, pp, av0);
            av1  = pk_fma(vf1, pp, av1);
            av2v = pk_fma(vf2, pp, av2v);
            av3  = pk_fma(vf3, pp, av3);
        }
        z += dpp_xor<0x128>(z);
        z += __shfl_xor(z, 16);
        z += __shfl_xor(z, 32);
        attn_combine(lane, d8, z, av0, av1, av2v, av3, orow);
    }
}

// ---------------------------------------------------------------- launch
extern "C" void kernel_launch(void* const* d_in, const int* in_sizes, int n_in,
                              void* d_out, int out_size, void* d_ws, size_t ws_size,
                              hipStream_t stream) {
    const int*   X    = (const int*)d_in[0];
    const int*   erow = (const int*)d_in[1];
    const int*   ecol = (const int*)d_in[2];
    const float* emb  = (const float*)d_in[3];
    const float* q_w  = (const float*)d_in[4];
    const float* q_b  = (const float*)d_in[5];
    const float* k_w  = (const float*)d_in[6];
    const float* k_b  = (const float*)d_in[7];
    const float* v_w  = (const float*)d_in[8];
    const float* v_b  = (const float*)d_in[9];
    const float* o_w  = (const float*)d_in[10];
    const float* o_b  = (const float*)d_in[11];
    float* out = (float*)d_out;

    char* ws = (char*)d_ws;
    bf16*   h    = (bf16*)(ws);
    bf16*   agg  = (bf16*)(ws);                 // aliases h (dead after QKV GEMM)
    ushort* qhp  = (ushort*)(ws + 10240000);
    ushort* kvhp = (ushort*)(ws + 20480000);
    bf16*   wqkv = (bf16*)(ws + 40960000);
    bf16*   wo   = (bf16*)(ws + 41353216);
    float*  qkvb = (float*)(ws + 41484288);
    int* row_ptr = (int*)(ws + 41487360);

    k_pre<<<6106, 256, 0, stream>>>(X, emb, h, q_w, k_w, v_w, o_w,
                                    q_b, k_b, v_b, wqkv, wo, qkvb, erow, row_ptr);

    // 1/sqrt(32) * log2(e): scores in log2 domain -> raw v_exp_f32 in k_attn.
    const float qscale = 0.25503486121587466f;
    dim3 gqkv((N_NODES + 127) / 128, 768 / 128);
    k_gemm_qkv<<<gqkv, 256, 0, stream>>>(h, wqkv, qkvb, qhp, kvhp, qscale);

    k_attn<<<N_NODES, 256, 0, stream>>>(row_ptr, ecol, qhp, kvhp, agg);

    dim3 go((N_NODES + 63) / 64, HIDDEN / 128);
    k_gemm_o<<<go, 256, 0, stream>>>(agg, wo, o_b, out);
}